// Round 11
// baseline (176.360 us; speedup 1.0000x reference)
//
#include <hip/hip_runtime.h>
#include <hip/hip_bf16.h>

// Nav_64939905516231 (VIN value iteration), MI355X gfx950.
// B=64,H=W=64,dim_h=150,n_hat=8,n_act=4,K=10. fp32 in/out, maze int32.
// Collapses: r = conv5x5(m,W_eff)+b_eff (150ch folded); q_t = q0 + conv5x5(v,w).
// 3 kernels: prep (1 blk: fold 150ch -> T[4][25]); rq (r + q0); vi (10 fused
// steps + projection, redundant shrinking-halo compute in LDS).
// Ladder: R4/R8 1024-thr -> VGPR64 -> GB spills (never 1024 thr). R7-R10
// 512-thr OWN=16: 49.6us, VALUBusy 32%, 2 waves/SIMD latency-bound; rq paid
// ~26us redundant W_eff per block. R11: prep split out; vi OWN=8 (512 blocks,
// 2 blk/CU -> 4 waves/SIMD); weights via scalar (uniform, const-index) global
// loads instead of LDS staging.

#define NHAT 8
#define DIMH 150

typedef float v2f __attribute__((ext_vector_type(2)));

// ---------------- prep: T[4][25] tap table + b_eff (1 block) ----------------
__global__ __launch_bounds__(128) void prep_kernel(
    const float* __restrict__ emb, const float* __restrict__ encode_w,
    const float* __restrict__ encode_b, const float* __restrict__ r_w,
    float* __restrict__ T, float* __restrict__ beff) {
  __shared__ float weff[2][25];
  int tid = threadIdx.x;
  if (tid < 50) {
    int i = tid / 25, k = tid % 25;
    float s = 0.f;
    for (int c = 0; c < DIMH; ++c)
      s += r_w[c] * encode_w[c * 50 + i * 25 + k];
    weff[i][k] = s;
  }
  if (tid == 64) {
    float s = 0.f;
    for (int c = 0; c < DIMH; ++c) s += r_w[c] * encode_b[c];
    *beff = s;
  }
  __syncthreads();
  if (tid < 100) {
    int val = tid / 25, k = tid % 25;
    float t = 0.f;
    if (val < 3) t = weff[0][k] * emb[val * 2] + weff[1][k] * emb[val * 2 + 1];
    T[val * 25 + k] = t;  // row 3 == 0 (padding sentinel)
  }
}

// ---------------- rq: r = table-conv(maze), q0 = conv5x5(r, q_w) -----------
__global__ __launch_bounds__(256) void rq_kernel(
    const int* __restrict__ maze, const float* __restrict__ Tg,
    const float* __restrict__ beffg, const float* __restrict__ q_w,
    float* __restrict__ q0g) {
  __shared__ float Ts[4][25];
  __shared__ float bsh;
  __shared__ v2f qw2[25][4];
  __shared__ unsigned char mzt[24][68];
  __shared__ float rt[20][68];

  int tid = threadIdx.x;
  int b = blockIdx.y, A0 = blockIdx.x * 16;

  if (tid < 100) Ts[tid / 25][tid % 25] = Tg[tid];
  if (tid == 100) bsh = *beffg;
  if (tid >= 128 && tid < 228) {
    int t2 = tid - 128;
    int k = t2 >> 2, j = t2 & 3;
    qw2[k][j] = (v2f){q_w[(2 * j) * 25 + k], q_w[(2 * j + 1) * 25 + k]};
  }
  for (int i = tid; i < 24 * 68; i += 256) {
    int mr = i / 68, mc = i % 68;
    int gy = A0 - 4 + mr, gx = mc - 2;
    unsigned char v = 3;
    if (gy >= 0 && gy < 64 && gx >= 0 && gx < 64)
      v = (unsigned char)maze[(b * 64 + gy) * 64 + gx];
    mzt[mr][mc] = v;
  }
  __syncthreads();
  // r tile rows [A0-2, A0+18): r(A0-2+rr, cc-2) taps mzt[rr+ky][cc-2+kx]
  for (int i = tid; i < 20 * 68; i += 256) {
    int rr = i / 68, cc = i % 68;
    int gy = A0 - 2 + rr, gx = cc - 2;
    float v = 0.f;
    if (gy >= 0 && gy < 64 && gx >= 0 && gx < 64) {
      v = bsh;
#pragma unroll
      for (int ky = 0; ky < 5; ++ky)
#pragma unroll
        for (int kx = 0; kx < 5; ++kx)
          v += Ts[mzt[rr + ky][cc - 2 + kx]][ky * 5 + kx];
    }
    rt[rr][cc] = v;
  }
  __syncthreads();
  for (int i = tid; i < 16 * 64; i += 256) {
    int ly = i >> 6, gx = i & 63;
    int gy = A0 + ly;
    v2f acc[4];
#pragma unroll
    for (int j = 0; j < 4; ++j) acc[j] = (v2f){0.f, 0.f};
#pragma unroll
    for (int ky = 0; ky < 5; ++ky)
#pragma unroll
      for (int kx = 0; kx < 5; ++kx) {
        int k = ky * 5 + kx;
        float vv = rt[ly + ky][gx + kx];
        v2f vv2 = (v2f){vv, vv};
#pragma unroll
        for (int j = 0; j < 4; ++j) acc[j] += qw2[k][j] * vv2;
      }
    float* dst = q0g + ((size_t)(b * 4096 + gy * 64 + gx)) * NHAT;
    ((float4*)dst)[0] = make_float4(acc[0].x, acc[0].y, acc[1].x, acc[1].y);
    ((float4*)dst)[1] = make_float4(acc[2].x, acc[2].y, acc[3].x, acc[3].y);
  }
}

// =============== vi: 10 fused VI steps + projection =================
// Block (512 thr = 8 waves) owns rows [a0, a0+8) of image b; grid 512 blocks
// = 2 blocks/CU -> 4 waves/SIMD. Wave = one 64-px row; lane = one pixel.
// v_t on shrinking region [max(0,a0-2(10-t)), min(64, a0+8+2(10-t))) in LDS
// (lr = gy-a0+20, 48 rows); q0 from global (L2), added after the conv.
// Weights read via uniform const-index global loads (scalar s_load path).
__global__ __launch_bounds__(512, 2) void vi_kernel(
    const float* __restrict__ q0g, const float* __restrict__ w,
    const float* __restrict__ fc_w, float* __restrict__ out) {
  __shared__ float vbuf[2][48][68];  // lds_row = gy - a0 + 20, col = gx + 2
  __shared__ float fcs[4][NHAT];

  int tid = threadIdx.x;
  int b = blockIdx.y, a0 = blockIdx.x * 8;
  int wave = tid >> 6, gx = tid & 63;

  if (tid >= 128 && tid < 160) {
    int t = tid - 128;
    fcs[t >> 3][t & 7] = fc_w[t];
  }
  for (int i = tid; i < 2 * 48 * 68; i += 512) ((float*)vbuf)[i] = 0.f;

  // weights -> registers/SGPRs via uniform constant-index loads
  v2f wr[4][25];
#pragma unroll
  for (int j = 0; j < 4; ++j)
#pragma unroll
    for (int k = 0; k < 25; ++k)
      wr[j][k] = (v2f){w[(2 * j) * 25 + k], w[(2 * j + 1) * 25 + k]};
  __syncthreads();

  const float* q0b = q0g + (size_t)b * 4096 * NHAT;
  int cur = 0;

  // v0 = max_c q0 on [a0-20, a0+28) clipped
  {
    int s = max(0, a0 - 20), e = min(64, a0 + 28);
    for (int r = s + wave; r < e; r += 8) {
      const float4* p = (const float4*)(q0b + ((size_t)r * 64 + gx) * NHAT);
      float4 f0 = p[0], f1 = p[1];
      float m = fmaxf(fmaxf(fmaxf(f0.x, f0.y), fmaxf(f0.z, f0.w)),
                      fmaxf(fmaxf(f1.x, f1.y), fmaxf(f1.z, f1.w)));
      vbuf[0][r - a0 + 20][gx + 2] = m;
    }
  }
  __syncthreads();

  for (int t = 1; t <= 10; ++t) {
    int hh = 2 * (10 - t);
    int s = max(0, a0 - hh), e = min(64, a0 + 8 + hh);
    for (int r = s + wave; r < e; r += 8) {
      int lr = r - a0 + 20;
      // issue q0 load now; first USE after the conv loop (latency hidden)
      const float4* p = (const float4*)(q0b + ((size_t)r * 64 + gx) * NHAT);
      float4 f0 = p[0], f1 = p[1];
      v2f a0v = (v2f){0.f, 0.f}, a1v = (v2f){0.f, 0.f};
      v2f a2v = (v2f){0.f, 0.f}, a3v = (v2f){0.f, 0.f};
#pragma unroll
      for (int ky = 0; ky < 5; ++ky) {
        const float* row = &vbuf[cur][lr - 2 + ky][gx];
#pragma unroll
        for (int kx = 0; kx < 5; ++kx) {
          int k = ky * 5 + kx;
          float vv = row[kx];
          v2f vv2 = (v2f){vv, vv};
          a0v += wr[0][k] * vv2;
          a1v += wr[1][k] * vv2;
          a2v += wr[2][k] * vv2;
          a3v += wr[3][k] * vv2;
        }
      }
      a0v += (v2f){f0.x, f0.y};
      a1v += (v2f){f0.z, f0.w};
      a2v += (v2f){f1.x, f1.y};
      a3v += (v2f){f1.z, f1.w};
      if (t < 10) {
        float m = fmaxf(fmaxf(fmaxf(a0v.x, a0v.y), fmaxf(a1v.x, a1v.y)),
                        fmaxf(fmaxf(a2v.x, a2v.y), fmaxf(a3v.x, a3v.y)));
        vbuf[cur ^ 1][lr][gx + 2] = m;
      } else {
        float4 o;
        float* op = &o.x;
#pragma unroll
        for (int a = 0; a < 4; ++a) {
          op[a] = fcs[a][0] * a0v.x + fcs[a][1] * a0v.y + fcs[a][2] * a1v.x +
                  fcs[a][3] * a1v.y + fcs[a][4] * a2v.x + fcs[a][5] * a2v.y +
                  fcs[a][6] * a3v.x + fcs[a][7] * a3v.y;
        }
        *(float4*)&out[((size_t)((b * 64 + r) * 64 + gx)) * 4] = o;
      }
    }
    cur ^= 1;
    if (t < 10) __syncthreads();
  }
}

extern "C" void kernel_launch(void* const* d_in, const int* in_sizes, int n_in,
                              void* d_out, int out_size, void* d_ws, size_t ws_size,
                              hipStream_t stream) {
  const int* maze = (const int*)d_in[0];
  const float* emb = (const float*)d_in[1];
  const float* encode_w = (const float*)d_in[2];
  const float* encode_b = (const float*)d_in[3];
  const float* r_w = (const float*)d_in[4];
  const float* q_w = (const float*)d_in[5];
  const float* w = (const float*)d_in[6];
  const float* fc_w = (const float*)d_in[7];
  float* out = (float*)d_out;

  float* wsf = (float*)d_ws;
  float* T = wsf;            // 100 floats
  float* beff = wsf + 100;   // 1 float
  float* q0 = wsf + 128;     // 8 MB

  prep_kernel<<<1, 128, 0, stream>>>(emb, encode_w, encode_b, r_w, T, beff);
  rq_kernel<<<dim3(4, 64), 256, 0, stream>>>(maze, T, beff, q_w, q0);
  vi_kernel<<<dim3(8, 64), 512, 0, stream>>>(q0, w, fc_w, out);
}

// Round 12
// 128.308 us; speedup vs baseline: 1.3745x; 1.3745x over previous
//
#include <hip/hip_runtime.h>
#include <hip/hip_bf16.h>

// Nav_64939905516231 (VIN value iteration), MI355X gfx950.
// B=64,H=W=64,dim_h=150,n_hat=8,n_act=4,K=10. fp32 in/out, maze int32.
// Collapses: r = conv5x5(m,W_eff)+b_eff (150ch folded); q_t = q0 + conv5x5(v,w).
// 3 kernels: prep (1 blk); rq (r+q0); vi (10 fused steps + projection,
// redundant shrinking-halo compute, OWN=16).
// Allocator ladder: 1024-thr -> VGPR 64 (GB spills). lb(512,2) -> VGPR 128,
// demand ~230 -> 24MB spill, 49.6us (R10). Global-uniform weights -> VGPR 40,
// per-iter reloads, 101us (R11). Observed pattern: VGPR = cap/2.
// R12: lb(512,1) -> cap 512 -> expect ~256: full wr[4][25] in regs, no spill.
// Fixed ~75us residual (harness 268MB ws-poison fill + overheads) is not ours.

#define NHAT 8
#define DIMH 150

typedef float v2f __attribute__((ext_vector_type(2)));

// ---------------- prep: T[4][25] tap table + b_eff (1 block) ----------------
__global__ __launch_bounds__(128) void prep_kernel(
    const float* __restrict__ emb, const float* __restrict__ encode_w,
    const float* __restrict__ encode_b, const float* __restrict__ r_w,
    float* __restrict__ T, float* __restrict__ beff) {
  __shared__ float weff[2][25];
  int tid = threadIdx.x;
  if (tid < 50) {
    int i = tid / 25, k = tid % 25;
    float s = 0.f;
    for (int c = 0; c < DIMH; ++c)
      s += r_w[c] * encode_w[c * 50 + i * 25 + k];
    weff[i][k] = s;
  }
  if (tid == 64) {
    float s = 0.f;
    for (int c = 0; c < DIMH; ++c) s += r_w[c] * encode_b[c];
    *beff = s;
  }
  __syncthreads();
  if (tid < 100) {
    int val = tid / 25, k = tid % 25;
    float t = 0.f;
    if (val < 3) t = weff[0][k] * emb[val * 2] + weff[1][k] * emb[val * 2 + 1];
    T[val * 25 + k] = t;  // row 3 == 0 (padding sentinel)
  }
}

// ---------------- rq: r = table-conv(maze), q0 = conv5x5(r, q_w) -----------
__global__ __launch_bounds__(256) void rq_kernel(
    const int* __restrict__ maze, const float* __restrict__ Tg,
    const float* __restrict__ beffg, const float* __restrict__ q_w,
    float* __restrict__ q0g) {
  __shared__ float Ts[4][25];
  __shared__ float bsh;
  __shared__ v2f qw2[25][4];
  __shared__ unsigned char mzt[24][68];
  __shared__ float rt[20][68];

  int tid = threadIdx.x;
  int b = blockIdx.y, A0 = blockIdx.x * 16;

  if (tid < 100) Ts[tid / 25][tid % 25] = Tg[tid];
  if (tid == 100) bsh = *beffg;
  if (tid >= 128 && tid < 228) {
    int t2 = tid - 128;
    int k = t2 >> 2, j = t2 & 3;
    qw2[k][j] = (v2f){q_w[(2 * j) * 25 + k], q_w[(2 * j + 1) * 25 + k]};
  }
  for (int i = tid; i < 24 * 68; i += 256) {
    int mr = i / 68, mc = i % 68;
    int gy = A0 - 4 + mr, gx = mc - 2;
    unsigned char v = 3;
    if (gy >= 0 && gy < 64 && gx >= 0 && gx < 64)
      v = (unsigned char)maze[(b * 64 + gy) * 64 + gx];
    mzt[mr][mc] = v;
  }
  __syncthreads();
  // r tile rows [A0-2, A0+18): r(A0-2+rr, cc-2) taps mzt[rr+ky][cc-2+kx]
  for (int i = tid; i < 20 * 68; i += 256) {
    int rr = i / 68, cc = i % 68;
    int gy = A0 - 2 + rr, gx = cc - 2;
    float v = 0.f;
    if (gy >= 0 && gy < 64 && gx >= 0 && gx < 64) {
      v = bsh;
#pragma unroll
      for (int ky = 0; ky < 5; ++ky)
#pragma unroll
        for (int kx = 0; kx < 5; ++kx)
          v += Ts[mzt[rr + ky][cc - 2 + kx]][ky * 5 + kx];
    }
    rt[rr][cc] = v;
  }
  __syncthreads();
  for (int i = tid; i < 16 * 64; i += 256) {
    int ly = i >> 6, gx = i & 63;
    int gy = A0 + ly;
    v2f acc[4];
#pragma unroll
    for (int j = 0; j < 4; ++j) acc[j] = (v2f){0.f, 0.f};
#pragma unroll
    for (int ky = 0; ky < 5; ++ky)
#pragma unroll
      for (int kx = 0; kx < 5; ++kx) {
        int k = ky * 5 + kx;
        float vv = rt[ly + ky][gx + kx];
        v2f vv2 = (v2f){vv, vv};
#pragma unroll
        for (int j = 0; j < 4; ++j) acc[j] += qw2[k][j] * vv2;
      }
    float* dst = q0g + ((size_t)(b * 4096 + gy * 64 + gx)) * NHAT;
    ((float4*)dst)[0] = make_float4(acc[0].x, acc[0].y, acc[1].x, acc[1].y);
    ((float4*)dst)[1] = make_float4(acc[2].x, acc[2].y, acc[3].x, acc[3].y);
  }
}

// =============== vi: 10 fused VI steps + projection =================
// Block (512 thr = 8 waves, 2/SIMD) owns rows [a0, a0+16) of image b.
// Wave = one 64-px row; lane = one pixel. v_t on the shrinking region
// [max(0,a0-2(10-t)), min(64, a0+16+2(10-t))) in LDS; q0 from global (L2),
// added after the conv. Weights: global -> wl2 (LDS) -> wr (registers).
// lb(512,1): VGPR cap 512 so the ~230-reg demand fits without spill.
__global__ __launch_bounds__(512, 1) void vi_kernel(
    const float* __restrict__ q0g, const float* __restrict__ w,
    const float* __restrict__ fc_w, float* __restrict__ out) {
  __shared__ float vbuf[2][64][68];  // lds_row = gy - a0 + 22, col = gx + 2
  __shared__ v2f wl2[25][4];
  __shared__ float fcs[4][NHAT];

  int tid = threadIdx.x;
  int b = blockIdx.y, a0 = blockIdx.x * 16;
  int wave = tid >> 6, gx = tid & 63;

  if (tid < 100) {
    int k = tid >> 2, j = tid & 3;
    wl2[k][j] = (v2f){w[(2 * j) * 25 + k], w[(2 * j + 1) * 25 + k]};
  } else if (tid >= 128 && tid < 160) {
    int t = tid - 128;
    fcs[t >> 3][t & 7] = fc_w[t];
  }
  for (int i = tid; i < 2 * 64 * 68; i += 512) ((float*)vbuf)[i] = 0.f;
  __syncthreads();

  // hoist weights LDS -> registers once (constant indices, fully unrolled)
  v2f wr[4][25];
#pragma unroll
  for (int k = 0; k < 25; ++k) {
#pragma unroll
    for (int j = 0; j < 4; ++j) wr[j][k] = wl2[k][j];
  }

  const float* q0b = q0g + (size_t)b * 4096 * NHAT;
  int cur = 0;

  // v0 = max_c q0 on [a0-20, a0+36) clipped
  {
    int s = max(0, a0 - 20), e = min(64, a0 + 36);
    for (int r = s + wave; r < e; r += 8) {
      const float4* p = (const float4*)(q0b + ((size_t)r * 64 + gx) * NHAT);
      float4 f0 = p[0], f1 = p[1];
      float m = fmaxf(fmaxf(fmaxf(f0.x, f0.y), fmaxf(f0.z, f0.w)),
                      fmaxf(fmaxf(f1.x, f1.y), fmaxf(f1.z, f1.w)));
      vbuf[0][r - a0 + 22][gx + 2] = m;
    }
  }
  __syncthreads();

  for (int t = 1; t <= 10; ++t) {
    int hh = 2 * (10 - t);
    int s = max(0, a0 - hh), e = min(64, a0 + 16 + hh);
    for (int r = s + wave; r < e; r += 8) {
      int lr = r - a0 + 22;
      // issue q0 load now; first USE after the conv loop (latency hidden)
      const float4* p = (const float4*)(q0b + ((size_t)r * 64 + gx) * NHAT);
      float4 f0 = p[0], f1 = p[1];
      v2f a0v = (v2f){0.f, 0.f}, a1v = (v2f){0.f, 0.f};
      v2f a2v = (v2f){0.f, 0.f}, a3v = (v2f){0.f, 0.f};
      // conv: taps from LDS (25 b32 reads), weights from registers
#pragma unroll
      for (int ky = 0; ky < 5; ++ky) {
        const float* row = &vbuf[cur][lr - 2 + ky][gx];
#pragma unroll
        for (int kx = 0; kx < 5; ++kx) {
          int k = ky * 5 + kx;
          float vv = row[kx];
          v2f vv2 = (v2f){vv, vv};
          a0v += wr[0][k] * vv2;
          a1v += wr[1][k] * vv2;
          a2v += wr[2][k] * vv2;
          a3v += wr[3][k] * vv2;
        }
      }
      // q0 added here -> vmcnt wait lands after the FMA chain
      a0v += (v2f){f0.x, f0.y};
      a1v += (v2f){f0.z, f0.w};
      a2v += (v2f){f1.x, f1.y};
      a3v += (v2f){f1.z, f1.w};
      if (t < 10) {
        float m = fmaxf(fmaxf(fmaxf(a0v.x, a0v.y), fmaxf(a1v.x, a1v.y)),
                        fmaxf(fmaxf(a2v.x, a2v.y), fmaxf(a3v.x, a3v.y)));
        vbuf[cur ^ 1][lr][gx + 2] = m;
      } else {
        float4 o;
        float* op = &o.x;
#pragma unroll
        for (int a = 0; a < 4; ++a) {
          op[a] = fcs[a][0] * a0v.x + fcs[a][1] * a0v.y + fcs[a][2] * a1v.x +
                  fcs[a][3] * a1v.y + fcs[a][4] * a2v.x + fcs[a][5] * a2v.y +
                  fcs[a][6] * a3v.x + fcs[a][7] * a3v.y;
        }
        *(float4*)&out[((size_t)((b * 64 + r) * 64 + gx)) * 4] = o;
      }
    }
    cur ^= 1;
    if (t < 10) __syncthreads();
  }
}

extern "C" void kernel_launch(void* const* d_in, const int* in_sizes, int n_in,
                              void* d_out, int out_size, void* d_ws, size_t ws_size,
                              hipStream_t stream) {
  const int* maze = (const int*)d_in[0];
  const float* emb = (const float*)d_in[1];
  const float* encode_w = (const float*)d_in[2];
  const float* encode_b = (const float*)d_in[3];
  const float* r_w = (const float*)d_in[4];
  const float* q_w = (const float*)d_in[5];
  const float* w = (const float*)d_in[6];
  const float* fc_w = (const float*)d_in[7];
  float* out = (float*)d_out;

  float* wsf = (float*)d_ws;
  float* T = wsf;            // 100 floats
  float* beff = wsf + 100;   // 1 float
  float* q0 = wsf + 128;     // 8 MB

  prep_kernel<<<1, 128, 0, stream>>>(emb, encode_w, encode_b, r_w, T, beff);
  rq_kernel<<<dim3(4, 64), 256, 0, stream>>>(maze, T, beff, q_w, q0);
  vi_kernel<<<dim3(4, 64), 512, 0, stream>>>(q0, w, fc_w, out);
}

// Round 13
// 123.666 us; speedup vs baseline: 1.4261x; 1.0375x over previous
//
#include <hip/hip_runtime.h>
#include <hip/hip_bf16.h>

// Nav_64939905516231 (VIN value iteration), MI355X gfx950.
// B=64,H=W=64,dim_h=150,n_hat=8,n_act=4,K=10. fp32 in/out, maze int32.
// Collapses: r = conv5x5(m,W_eff)+b_eff (150ch folded); q_t = q0 + conv5x5(v,w).
// prep (1 blk) -> rq (r+q0) -> vi (10 fused steps + projection, redundant
// shrinking-halo compute, OWN=16).
// Allocator facts (R4..R12): 1024-thr => VGPR 64; 512-thr => VGPR 128 no
// matter the launch_bounds. 8ch weights/lane = 200 floats can NEVER be
// register-resident -> spills (24MB scratch, ~92 reloads/iter, 50us).
// R13: channel-split across wave pairs: wave=(slot,half); each wave does 4
// channels (100 weight floats, fits 128) over full rows; halves combine via
// LDS tmp + the per-step barrier. No scratch. Cost model: per-CU LDS issue
// ~5.8cyc/instr -> vi ~2*324 row-halves*16 instr ~ 26us.

#define NHAT 8
#define DIMH 150

typedef float v2f __attribute__((ext_vector_type(2)));

// ---------------- prep: T[4][25] tap table + b_eff (1 block) ----------------
__global__ __launch_bounds__(128) void prep_kernel(
    const float* __restrict__ emb, const float* __restrict__ encode_w,
    const float* __restrict__ encode_b, const float* __restrict__ r_w,
    float* __restrict__ T, float* __restrict__ beff) {
  __shared__ float weff[2][25];
  int tid = threadIdx.x;
  if (tid < 50) {
    int i = tid / 25, k = tid % 25;
    float s = 0.f;
    for (int c = 0; c < DIMH; ++c)
      s += r_w[c] * encode_w[c * 50 + i * 25 + k];
    weff[i][k] = s;
  }
  if (tid == 64) {
    float s = 0.f;
    for (int c = 0; c < DIMH; ++c) s += r_w[c] * encode_b[c];
    *beff = s;
  }
  __syncthreads();
  if (tid < 100) {
    int val = tid / 25, k = tid % 25;
    float t = 0.f;
    if (val < 3) t = weff[0][k] * emb[val * 2] + weff[1][k] * emb[val * 2 + 1];
    T[val * 25 + k] = t;  // row 3 == 0 (padding sentinel)
  }
}

// ---------------- rq: r = table-conv(maze), q0 = conv5x5(r, q_w) -----------
__global__ __launch_bounds__(512) void rq_kernel(
    const int* __restrict__ maze, const float* __restrict__ Tg,
    const float* __restrict__ beffg, const float* __restrict__ q_w,
    float* __restrict__ q0g) {
  __shared__ float Ts[4][25];
  __shared__ float bsh;
  __shared__ v2f qw2[25][4];
  __shared__ unsigned char mzt[24][68];
  __shared__ float rt[20][68];

  int tid = threadIdx.x;
  int b = blockIdx.y, A0 = blockIdx.x * 16;

  if (tid < 100) Ts[tid / 25][tid % 25] = Tg[tid];
  if (tid == 100) bsh = *beffg;
  if (tid >= 128 && tid < 228) {
    int t2 = tid - 128;
    int k = t2 >> 2, j = t2 & 3;
    qw2[k][j] = (v2f){q_w[(2 * j) * 25 + k], q_w[(2 * j + 1) * 25 + k]};
  }
  for (int i = tid; i < 24 * 68; i += 512) {
    int mr = i / 68, mc = i % 68;
    int gy = A0 - 4 + mr, gx = mc - 2;
    unsigned char v = 3;
    if (gy >= 0 && gy < 64 && gx >= 0 && gx < 64)
      v = (unsigned char)maze[(b * 64 + gy) * 64 + gx];
    mzt[mr][mc] = v;
  }
  __syncthreads();
  // r tile rows [A0-2, A0+18): r(A0-2+rr, cc-2) taps mzt[rr+ky][cc-2+kx]
  for (int i = tid; i < 20 * 68; i += 512) {
    int rr = i / 68, cc = i % 68;
    int gy = A0 - 2 + rr, gx = cc - 2;
    float v = 0.f;
    if (gy >= 0 && gy < 64 && gx >= 0 && gx < 64) {
      v = bsh;
#pragma unroll
      for (int ky = 0; ky < 5; ++ky)
#pragma unroll
        for (int kx = 0; kx < 5; ++kx)
          v += Ts[mzt[rr + ky][cc - 2 + kx]][ky * 5 + kx];
    }
    rt[rr][cc] = v;
  }
  __syncthreads();
  for (int i = tid; i < 16 * 64; i += 512) {
    int ly = i >> 6, gx = i & 63;
    int gy = A0 + ly;
    v2f acc[4];
#pragma unroll
    for (int j = 0; j < 4; ++j) acc[j] = (v2f){0.f, 0.f};
#pragma unroll
    for (int ky = 0; ky < 5; ++ky)
#pragma unroll
      for (int kx = 0; kx < 5; ++kx) {
        int k = ky * 5 + kx;
        float vv = rt[ly + ky][gx + kx];
        v2f vv2 = (v2f){vv, vv};
#pragma unroll
        for (int j = 0; j < 4; ++j) acc[j] += qw2[k][j] * vv2;
      }
    float* dst = q0g + ((size_t)(b * 4096 + gy * 64 + gx)) * NHAT;
    ((float4*)dst)[0] = make_float4(acc[0].x, acc[0].y, acc[1].x, acc[1].y);
    ((float4*)dst)[1] = make_float4(acc[2].x, acc[2].y, acc[3].x, acc[3].y);
  }
}

// =============== vi: 10 fused VI steps + projection =================
// Block (512 thr = 8 waves) owns rows [a0, a0+16) of image b. Wave =
// (slot = wave>>1 in 0..3, half = wave&1). Each wave: rows r = s+slot (+=4),
// channels 4*half..4*half+3 (weights = 100 floats in registers). Halves
// combine per row through LDS tmp around the per-step barrier.
// lr = r - a0 + 22; vbuf rows 0..59 used; tmp row = lr-4 in [0,52).
__global__ __launch_bounds__(512, 2) void vi_kernel(
    const float* __restrict__ q0g, const float* __restrict__ w,
    const float* __restrict__ fc_w, float* __restrict__ out) {
  __shared__ float vbuf[2][60][68];            // 32.6 KB
  __shared__ __align__(16) float tmp[52][2][64];  // 26.6 KB (reused for proj)
  __shared__ v2f wl2[25][4];

  int tid = threadIdx.x;
  int b = blockIdx.y, a0 = blockIdx.x * 16;
  int wave = tid >> 6, gx = tid & 63;
  int half = wave & 1, slot = wave >> 1;

  if (tid < 100) {
    int k = tid >> 2, j = tid & 3;
    wl2[k][j] = (v2f){w[(2 * j) * 25 + k], w[(2 * j + 1) * 25 + k]};
  }
  for (int i = tid; i < 2 * 60 * 68; i += 512) ((float*)vbuf)[i] = 0.f;
  __syncthreads();

  // this wave's 4 channels -> 50 v2f = 100 floats in registers
  v2f wr0[25], wr1[25];
#pragma unroll
  for (int k = 0; k < 25; ++k) {
    wr0[k] = wl2[k][2 * half];
    wr1[k] = wl2[k][2 * half + 1];
  }

  const float* q0b = q0g + (size_t)b * 4096 * NHAT;
  int cur = 0;

  // v0 = max_c q0 on [a0-20, a0+36): full 8ch per lane, waves stride 8 rows
  {
    int s = max(0, a0 - 20), e = min(64, a0 + 36);
    for (int r = s + wave; r < e; r += 8) {
      const float4* p = (const float4*)(q0b + ((size_t)r * 64 + gx) * NHAT);
      float4 f0 = p[0], f1 = p[1];
      float m = fmaxf(fmaxf(fmaxf(f0.x, f0.y), fmaxf(f0.z, f0.w)),
                      fmaxf(fmaxf(f1.x, f1.y), fmaxf(f1.z, f1.w)));
      vbuf[0][r - a0 + 22][gx + 2] = m;
    }
  }
  __syncthreads();

  for (int t = 1; t <= 9; ++t) {
    int hh = 2 * (10 - t);
    int s = max(0, a0 - hh), e = min(64, a0 + 16 + hh);
    // phase A: each wave -> half-max for its rows/channels
    for (int r = s + slot; r < e; r += 4) {
      int lr = r - a0 + 22;
      const float4* p =
          (const float4*)(q0b + ((size_t)r * 64 + gx) * NHAT + half * 4);
      float4 q4 = *p;  // 4 channels of q0
      v2f acc0 = (v2f){0.f, 0.f}, acc1 = (v2f){0.f, 0.f};
#pragma unroll
      for (int ky = 0; ky < 5; ++ky) {
        const float* row = &vbuf[cur][lr - 2 + ky][gx];
#pragma unroll
        for (int kx = 0; kx < 5; ++kx) {
          float vv = row[kx];
          v2f vv2 = (v2f){vv, vv};
          acc0 += wr0[ky * 5 + kx] * vv2;
          acc1 += wr1[ky * 5 + kx] * vv2;
        }
      }
      acc0 += (v2f){q4.x, q4.y};
      acc1 += (v2f){q4.z, q4.w};
      float m = fmaxf(fmaxf(acc0.x, acc0.y), fmaxf(acc1.x, acc1.y));
      tmp[lr - 4][half][gx] = m;
    }
    __syncthreads();
    // phase B: combine halves -> vbuf[cur^1]
    int n = e - s;
    for (int idx = tid; idx < n * 64; idx += 512) {
      int rr = idx >> 6, px = idx & 63;
      int lr2 = s - a0 + 22 + rr;
      float m = fmaxf(tmp[lr2 - 4][0][px], tmp[lr2 - 4][1][px]);
      vbuf[cur ^ 1][lr2][px + 2] = m;
    }
    __syncthreads();
    cur ^= 1;
  }

  // final step t=10 fused with projection: rows [a0, a0+16)
  float fcp[4][4];
#pragma unroll
  for (int a = 0; a < 4; ++a)
#pragma unroll
    for (int cc = 0; cc < 4; ++cc) fcp[a][cc] = fc_w[a * 8 + 4 * half + cc];
  float* projtmp = (float*)tmp;  // [slot*64+gx]*4, 4KB per sub-iter

#pragma unroll
  for (int i = 0; i < 4; ++i) {
    int r = a0 + slot + 4 * i;
    int lr = r - a0 + 22;
    const float4* p =
        (const float4*)(q0b + ((size_t)r * 64 + gx) * NHAT + half * 4);
    float4 q4 = *p;
    v2f acc0 = (v2f){0.f, 0.f}, acc1 = (v2f){0.f, 0.f};
#pragma unroll
    for (int ky = 0; ky < 5; ++ky) {
      const float* row = &vbuf[cur][lr - 2 + ky][gx];
#pragma unroll
      for (int kx = 0; kx < 5; ++kx) {
        float vv = row[kx];
        v2f vv2 = (v2f){vv, vv};
        acc0 += wr0[ky * 5 + kx] * vv2;
        acc1 += wr1[ky * 5 + kx] * vv2;
      }
    }
    float q0v = acc0.x + q4.x, q1v = acc0.y + q4.y;
    float q2v = acc1.x + q4.z, q3v = acc1.y + q4.w;
    float4 pp;
    pp.x = fcp[0][0] * q0v + fcp[0][1] * q1v + fcp[0][2] * q2v + fcp[0][3] * q3v;
    pp.y = fcp[1][0] * q0v + fcp[1][1] * q1v + fcp[1][2] * q2v + fcp[1][3] * q3v;
    pp.z = fcp[2][0] * q0v + fcp[2][1] * q1v + fcp[2][2] * q2v + fcp[2][3] * q3v;
    pp.w = fcp[3][0] * q0v + fcp[3][1] * q1v + fcp[3][2] * q2v + fcp[3][3] * q3v;
    if (half == 1) *(float4*)&projtmp[(slot * 64 + gx) * 4] = pp;
    __syncthreads();
    if (half == 0) {
      float4 o = *(const float4*)&projtmp[(slot * 64 + gx) * 4];
      o.x += pp.x; o.y += pp.y; o.z += pp.z; o.w += pp.w;
      *(float4*)&out[((size_t)((b * 64 + r) * 64 + gx)) * 4] = o;
    }
    __syncthreads();
  }
}

extern "C" void kernel_launch(void* const* d_in, const int* in_sizes, int n_in,
                              void* d_out, int out_size, void* d_ws, size_t ws_size,
                              hipStream_t stream) {
  const int* maze = (const int*)d_in[0];
  const float* emb = (const float*)d_in[1];
  const float* encode_w = (const float*)d_in[2];
  const float* encode_b = (const float*)d_in[3];
  const float* r_w = (const float*)d_in[4];
  const float* q_w = (const float*)d_in[5];
  const float* w = (const float*)d_in[6];
  const float* fc_w = (const float*)d_in[7];
  float* out = (float*)d_out;

  float* wsf = (float*)d_ws;
  float* T = wsf;            // 100 floats
  float* beff = wsf + 100;   // 1 float
  float* q0 = wsf + 128;     // 8 MB

  prep_kernel<<<1, 128, 0, stream>>>(emb, encode_w, encode_b, r_w, T, beff);
  rq_kernel<<<dim3(4, 64), 512, 0, stream>>>(maze, T, beff, q_w, q0);
  vi_kernel<<<dim3(4, 64), 512, 0, stream>>>(q0, w, fc_w, out);
}

// Round 14
// 123.541 us; speedup vs baseline: 1.4276x; 1.0010x over previous
//
#include <hip/hip_runtime.h>
#include <hip/hip_bf16.h>

// Nav_64939905516231 (VIN value iteration), MI355X gfx950.
// B=64,H=W=64,dim_h=150,n_hat=8,n_act=4,K=10. fp32 in/out, maze int32.
// Collapses: r = conv5x5(m,W_eff)+b_eff (150ch folded); q_t = q0 + conv5x5(v,w).
// prep (1 blk) -> rq (r+q0) -> vi (10 fused steps + projection, redundant
// shrinking-halo compute, OWN=16, channel-split across wave pairs).
// Facts: 1024-thr => VGPR 64 (GB spills). 512-thr => VGPR<=128 regardless of
// launch_bounds; 200 weight floats/lane always spill; 100 fit (via AGPRs).
// R13 (channel-split, no spill) = 47.8us, LDS-ISSUE-BOUND: 676 row-halves/CU
// x 26 instr x 5.8cyc = 102k cyc = 42us ~ observed. ~75us of total is fixed
// harness floor (ws re-poison 43us + overheads).
// R14: adjacent-row PAIRING: one wave computes rows (r0,r0+1): 6 input rows
// x 5 taps = 30 reads / 2 outputs (15/output vs 26) and weight regs reused
// across both rows. Model: 338 pairs x ~186 cyc = 63k cyc -> vi ~30us.

#define NHAT 8
#define DIMH 150

typedef float v2f __attribute__((ext_vector_type(2)));

// ---------------- prep: T[4][25] tap table + b_eff (1 block) ----------------
__global__ __launch_bounds__(128) void prep_kernel(
    const float* __restrict__ emb, const float* __restrict__ encode_w,
    const float* __restrict__ encode_b, const float* __restrict__ r_w,
    float* __restrict__ T, float* __restrict__ beff) {
  __shared__ float weff[2][25];
  int tid = threadIdx.x;
  if (tid < 50) {
    int i = tid / 25, k = tid % 25;
    float s = 0.f;
    for (int c = 0; c < DIMH; ++c)
      s += r_w[c] * encode_w[c * 50 + i * 25 + k];
    weff[i][k] = s;
  }
  if (tid == 64) {
    float s = 0.f;
    for (int c = 0; c < DIMH; ++c) s += r_w[c] * encode_b[c];
    *beff = s;
  }
  __syncthreads();
  if (tid < 100) {
    int val = tid / 25, k = tid % 25;
    float t = 0.f;
    if (val < 3) t = weff[0][k] * emb[val * 2] + weff[1][k] * emb[val * 2 + 1];
    T[val * 25 + k] = t;  // row 3 == 0 (padding sentinel)
  }
}

// ---------------- rq: r = table-conv(maze), q0 = conv5x5(r, q_w) -----------
__global__ __launch_bounds__(512) void rq_kernel(
    const int* __restrict__ maze, const float* __restrict__ Tg,
    const float* __restrict__ beffg, const float* __restrict__ q_w,
    float* __restrict__ q0g) {
  __shared__ float Ts[4][25];
  __shared__ float bsh;
  __shared__ v2f qw2[25][4];
  __shared__ unsigned char mzt[24][68];
  __shared__ float rt[20][68];

  int tid = threadIdx.x;
  int b = blockIdx.y, A0 = blockIdx.x * 16;

  if (tid < 100) Ts[tid / 25][tid % 25] = Tg[tid];
  if (tid == 100) bsh = *beffg;
  if (tid >= 128 && tid < 228) {
    int t2 = tid - 128;
    int k = t2 >> 2, j = t2 & 3;
    qw2[k][j] = (v2f){q_w[(2 * j) * 25 + k], q_w[(2 * j + 1) * 25 + k]};
  }
  for (int i = tid; i < 24 * 68; i += 512) {
    int mr = i / 68, mc = i % 68;
    int gy = A0 - 4 + mr, gx = mc - 2;
    unsigned char v = 3;
    if (gy >= 0 && gy < 64 && gx >= 0 && gx < 64)
      v = (unsigned char)maze[(b * 64 + gy) * 64 + gx];
    mzt[mr][mc] = v;
  }
  __syncthreads();
  // r tile rows [A0-2, A0+18): r(A0-2+rr, cc-2) taps mzt[rr+ky][cc-2+kx]
  for (int i = tid; i < 20 * 68; i += 512) {
    int rr = i / 68, cc = i % 68;
    int gy = A0 - 2 + rr, gx = cc - 2;
    float v = 0.f;
    if (gy >= 0 && gy < 64 && gx >= 0 && gx < 64) {
      v = bsh;
#pragma unroll
      for (int ky = 0; ky < 5; ++ky)
#pragma unroll
        for (int kx = 0; kx < 5; ++kx)
          v += Ts[mzt[rr + ky][cc - 2 + kx]][ky * 5 + kx];
    }
    rt[rr][cc] = v;
  }
  __syncthreads();
  for (int i = tid; i < 16 * 64; i += 512) {
    int ly = i >> 6, gx = i & 63;
    int gy = A0 + ly;
    v2f acc[4];
#pragma unroll
    for (int j = 0; j < 4; ++j) acc[j] = (v2f){0.f, 0.f};
#pragma unroll
    for (int ky = 0; ky < 5; ++ky)
#pragma unroll
      for (int kx = 0; kx < 5; ++kx) {
        int k = ky * 5 + kx;
        float vv = rt[ly + ky][gx + kx];
        v2f vv2 = (v2f){vv, vv};
#pragma unroll
        for (int j = 0; j < 4; ++j) acc[j] += qw2[k][j] * vv2;
      }
    float* dst = q0g + ((size_t)(b * 4096 + gy * 64 + gx)) * NHAT;
    ((float4*)dst)[0] = make_float4(acc[0].x, acc[0].y, acc[1].x, acc[1].y);
    ((float4*)dst)[1] = make_float4(acc[2].x, acc[2].y, acc[3].x, acc[3].y);
  }
}

// =============== vi: 10 fused VI steps + projection =================
// Block (512 thr = 8 waves) owns rows [a0, a0+16) of image b. Wave =
// (slot = wave>>1 in 0..3, half = wave&1). Each wave-iter computes TWO
// adjacent rows r0 = s + 2*slot + 8*i, r1 = r0+1 for its 4 channels
// (weights 100 floats, register/AGPR-resident). 6 input rows x 5 taps serve
// both rows. Halves combine per row through LDS tmp at the step barrier.
// lr = r - a0 + 22; vbuf rows [2,58); tmp row = lr-4 in [0,52).
__global__ __launch_bounds__(512, 2) void vi_kernel(
    const float* __restrict__ q0g, const float* __restrict__ w,
    const float* __restrict__ fc_w, float* __restrict__ out) {
  __shared__ float vbuf[2][60][68];               // 32.6 KB
  __shared__ __align__(16) float tmp[52][2][64];  // 26.6 KB (reused for proj)
  __shared__ v2f wl2[25][4];

  int tid = threadIdx.x;
  int b = blockIdx.y, a0 = blockIdx.x * 16;
  int wave = tid >> 6, gx = tid & 63;
  int half = wave & 1, slot = wave >> 1;

  if (tid < 100) {
    int k = tid >> 2, j = tid & 3;
    wl2[k][j] = (v2f){w[(2 * j) * 25 + k], w[(2 * j + 1) * 25 + k]};
  }
  for (int i = tid; i < 2 * 60 * 68; i += 512) ((float*)vbuf)[i] = 0.f;
  __syncthreads();

  // this wave's 4 channels -> 50 v2f = 100 floats in registers/AGPRs
  v2f wr0[25], wr1[25];
#pragma unroll
  for (int k = 0; k < 25; ++k) {
    wr0[k] = wl2[k][2 * half];
    wr1[k] = wl2[k][2 * half + 1];
  }

  const float* q0b = q0g + (size_t)b * 4096 * NHAT;
  int cur = 0;

  // v0 = max_c q0 on [a0-20, a0+36): full 8ch per lane, waves stride 8 rows
  {
    int s = max(0, a0 - 20), e = min(64, a0 + 36);
    for (int r = s + wave; r < e; r += 8) {
      const float4* p = (const float4*)(q0b + ((size_t)r * 64 + gx) * NHAT);
      float4 f0 = p[0], f1 = p[1];
      float m = fmaxf(fmaxf(fmaxf(f0.x, f0.y), fmaxf(f0.z, f0.w)),
                      fmaxf(fmaxf(f1.x, f1.y), fmaxf(f1.z, f1.w)));
      vbuf[0][r - a0 + 22][gx + 2] = m;
    }
  }
  __syncthreads();

  for (int t = 1; t <= 9; ++t) {
    int hh = 2 * (10 - t);
    int s = max(0, a0 - hh), e = min(64, a0 + 16 + hh);
    // phase A: each wave -> half-max for row pair (r0, r0+1), its 4 channels
    for (int r0 = s + 2 * slot; r0 < e; r0 += 8) {
      int r1 = r0 + 1;            // may be >= e (write guarded)
      int lr0 = r0 - a0 + 22;
      // issue q0 loads early (wave-uniform branch on r1)
      const float4* p0 =
          (const float4*)(q0b + ((size_t)r0 * 64 + gx) * NHAT + half * 4);
      float4 qa = *p0;
      float4 qb = make_float4(0.f, 0.f, 0.f, 0.f);
      if (r1 < e)
        qb = *(const float4*)(q0b + ((size_t)r1 * 64 + gx) * NHAT + half * 4);
      v2f A0 = (v2f){0.f, 0.f}, A1 = (v2f){0.f, 0.f};
      v2f B0 = (v2f){0.f, 0.f}, B1 = (v2f){0.f, 0.f};
      // 6 input rows serve both outputs: r0 uses jj=0..4 (ky=jj),
      // r1 uses jj=1..5 (ky=jj-1)
#pragma unroll
      for (int jj = 0; jj < 6; ++jj) {
        const float* row = &vbuf[cur][lr0 - 2 + jj][gx];
#pragma unroll
        for (int kx = 0; kx < 5; ++kx) {
          float vv = row[kx];
          v2f vv2 = (v2f){vv, vv};
          if (jj < 5) {
            int k = jj * 5 + kx;
            A0 += wr0[k] * vv2;
            A1 += wr1[k] * vv2;
          }
          if (jj >= 1) {
            int k = (jj - 1) * 5 + kx;
            B0 += wr0[k] * vv2;
            B1 += wr1[k] * vv2;
          }
        }
      }
      A0 += (v2f){qa.x, qa.y};
      A1 += (v2f){qa.z, qa.w};
      float m0 = fmaxf(fmaxf(A0.x, A0.y), fmaxf(A1.x, A1.y));
      tmp[lr0 - 4][half][gx] = m0;
      if (r1 < e) {
        B0 += (v2f){qb.x, qb.y};
        B1 += (v2f){qb.z, qb.w};
        float m1 = fmaxf(fmaxf(B0.x, B0.y), fmaxf(B1.x, B1.y));
        tmp[lr0 - 3][half][gx] = m1;
      }
    }
    __syncthreads();
    // phase B: combine halves -> vbuf[cur^1]
    int n = e - s;
    for (int idx = tid; idx < n * 64; idx += 512) {
      int rr = idx >> 6, px = idx & 63;
      int lr2 = s - a0 + 22 + rr;
      vbuf[cur ^ 1][lr2][px + 2] =
          fmaxf(tmp[lr2 - 4][0][px], tmp[lr2 - 4][1][px]);
    }
    __syncthreads();
    cur ^= 1;
  }

  // final step t=10 fused with projection: rows [a0, a0+16), paired
  float fcp[4][4];
#pragma unroll
  for (int a = 0; a < 4; ++a)
#pragma unroll
    for (int cc = 0; cc < 4; ++cc) fcp[a][cc] = fc_w[a * 8 + 4 * half + cc];
  float* proj = (float*)tmp;  // reused as proj[8][64][4] = 8 KB

#pragma unroll
  for (int i = 0; i < 2; ++i) {
    int r0 = a0 + 2 * slot + 8 * i;
    int r1 = r0 + 1;  // always < a0+16
    int lr0 = r0 - a0 + 22;
    const float4* p0 =
        (const float4*)(q0b + ((size_t)r0 * 64 + gx) * NHAT + half * 4);
    float4 qa = *p0;
    float4 qb =
        *(const float4*)(q0b + ((size_t)r1 * 64 + gx) * NHAT + half * 4);
    v2f A0 = (v2f){0.f, 0.f}, A1 = (v2f){0.f, 0.f};
    v2f B0 = (v2f){0.f, 0.f}, B1 = (v2f){0.f, 0.f};
#pragma unroll
    for (int jj = 0; jj < 6; ++jj) {
      const float* row = &vbuf[cur][lr0 - 2 + jj][gx];
#pragma unroll
      for (int kx = 0; kx < 5; ++kx) {
        float vv = row[kx];
        v2f vv2 = (v2f){vv, vv};
        if (jj < 5) {
          int k = jj * 5 + kx;
          A0 += wr0[k] * vv2;
          A1 += wr1[k] * vv2;
        }
        if (jj >= 1) {
          int k = (jj - 1) * 5 + kx;
          B0 += wr0[k] * vv2;
          B1 += wr1[k] * vv2;
        }
      }
    }
    float q0v = A0.x + qa.x, q1v = A0.y + qa.y;
    float q2v = A1.x + qa.z, q3v = A1.y + qa.w;
    float4 pa;
    pa.x = fcp[0][0] * q0v + fcp[0][1] * q1v + fcp[0][2] * q2v + fcp[0][3] * q3v;
    pa.y = fcp[1][0] * q0v + fcp[1][1] * q1v + fcp[1][2] * q2v + fcp[1][3] * q3v;
    pa.z = fcp[2][0] * q0v + fcp[2][1] * q1v + fcp[2][2] * q2v + fcp[2][3] * q3v;
    pa.w = fcp[3][0] * q0v + fcp[3][1] * q1v + fcp[3][2] * q2v + fcp[3][3] * q3v;
    q0v = B0.x + qb.x; q1v = B0.y + qb.y;
    q2v = B1.x + qb.z; q3v = B1.y + qb.w;
    float4 pb;
    pb.x = fcp[0][0] * q0v + fcp[0][1] * q1v + fcp[0][2] * q2v + fcp[0][3] * q3v;
    pb.y = fcp[1][0] * q0v + fcp[1][1] * q1v + fcp[1][2] * q2v + fcp[1][3] * q3v;
    pb.z = fcp[2][0] * q0v + fcp[2][1] * q1v + fcp[2][2] * q2v + fcp[2][3] * q3v;
    pb.w = fcp[3][0] * q0v + fcp[3][1] * q1v + fcp[3][2] * q2v + fcp[3][3] * q3v;
    int i0 = (r0 - a0) & 7, i1 = (r1 - a0) & 7;
    if (half == 1) {
      *(float4*)&proj[(i0 * 64 + gx) * 4] = pa;
      *(float4*)&proj[(i1 * 64 + gx) * 4] = pb;
    }
    __syncthreads();
    if (half == 0) {
      float4 oa = *(const float4*)&proj[(i0 * 64 + gx) * 4];
      float4 ob = *(const float4*)&proj[(i1 * 64 + gx) * 4];
      oa.x += pa.x; oa.y += pa.y; oa.z += pa.z; oa.w += pa.w;
      ob.x += pb.x; ob.y += pb.y; ob.z += pb.z; ob.w += pb.w;
      *(float4*)&out[((size_t)((b * 64 + r0) * 64 + gx)) * 4] = oa;
      *(float4*)&out[((size_t)((b * 64 + r1) * 64 + gx)) * 4] = ob;
    }
    __syncthreads();
  }
}

extern "C" void kernel_launch(void* const* d_in, const int* in_sizes, int n_in,
                              void* d_out, int out_size, void* d_ws, size_t ws_size,
                              hipStream_t stream) {
  const int* maze = (const int*)d_in[0];
  const float* emb = (const float*)d_in[1];
  const float* encode_w = (const float*)d_in[2];
  const float* encode_b = (const float*)d_in[3];
  const float* r_w = (const float*)d_in[4];
  const float* q_w = (const float*)d_in[5];
  const float* w = (const float*)d_in[6];
  const float* fc_w = (const float*)d_in[7];
  float* out = (float*)d_out;

  float* wsf = (float*)d_ws;
  float* T = wsf;            // 100 floats
  float* beff = wsf + 100;   // 1 float
  float* q0 = wsf + 128;     // 8 MB

  prep_kernel<<<1, 128, 0, stream>>>(emb, encode_w, encode_b, r_w, T, beff);
  rq_kernel<<<dim3(4, 64), 512, 0, stream>>>(maze, T, beff, q_w, q0);
  vi_kernel<<<dim3(4, 64), 512, 0, stream>>>(q0, w, fc_w, out);
}